// Round 18
// baseline (675.928 us; speedup 1.0000x reference)
//
#include <hip/hip_runtime.h>

typedef unsigned short u16;
typedef unsigned int   u32;
typedef __attribute__((ext_vector_type(8))) short short8;
typedef __attribute__((ext_vector_type(4))) float f32x4;

#define IMG_BYTES  557568      /* 66*66*64*2 (padded bf16 image) */
#define WS_SCALE   0
#define WS_SHIFT   256
#define WS_BTAB    512                       /* 9*192*4 = 6912 B */
#define WS_PART2   7424                      /* 128*4 = 512 B */
#define WS_WA      8704                      /* 54 (27st x 2oh) * 12288 B */
#define WS_BNXP    672256                    /* 64 * IMG_BYTES */
#define WS_HC      (WS_BNXP + (size_t)64*IMG_BYTES)
#define WS_CSTATE  (WS_HC + (size_t)16*IMG_BYTES)    /* 4 MiB */
#define WS_PARTB   (WS_CSTATE + 4194304ULL)          /* 128 KiB */

__device__ __forceinline__ u16 f2b(float f){
  u32 x = __float_as_uint(f);
  return (u16)((x + 0x7fffu + ((x>>16)&1u)) >> 16);
}
__device__ __forceinline__ float b2f(u16 u){ return __uint_as_float(((u32)u)<<16); }
__device__ __forceinline__ float sigm(float x){ return 1.f/(1.f+__expf(-x)); }
__device__ __forceinline__ float tanh_(float x){
  float e = __expf(2.f*fabsf(x));
  float t = 1.f - 2.f/(e+1.f);
  return copysignf(t, x);
}

/* ---- weight transform: conv1 weights pre-scaled by BN scale[c] ---- */
__global__ void k_wt(const float* __restrict__ c1, const float* __restrict__ c2h,
                     const float* __restrict__ h2h, const float* __restrict__ scale,
                     u16* __restrict__ wA){
  int idx = blockIdx.x*256 + threadIdx.x;   /* 1296*256 = 331776 exact */
  int e = idx & 7;
  int lane = (idx >> 3) & 63;
  int v = idx >> 9;
  int f2 = v % 12;  v /= 12;
  int oh = v & 1;
  int stage = v >> 1;
  int cc = f2 / 6, gate = (f2 % 6) >> 1, og2 = f2 & 1;
  int j = stage / 9, tap = stage % 9;
  int och = gate*64 + (oh*2 + og2)*16 + (lane & 15);
  int c = cc*32 + (lane >> 4)*8 + e;
  const float* src = (j==0) ? c1 : ((j==1) ? c2h : h2h);
  float vv = src[(och*64 + c)*9 + tap];
  if (j == 0) vv *= scale[c];
  wA[idx] = f2b(vv);
}

/* ---- pure transpose: x f32 NCHW -> raw bf16 padded [img][66][66][64] ---- */
__global__ void k_xt(const float* __restrict__ x, char* __restrict__ xp){
  int img = blockIdx.x / 66, rp = blockIdx.x % 66;
  int tid = threadIdx.x;
  char* dstrow = xp + (size_t)img*IMG_BYTES + (size_t)rp*8448;
  const uint4 z = {0,0,0,0};
  if (rp == 0 || rp == 65){
    for (int i = tid; i < 528; i += 256) ((uint4*)dstrow)[i] = z;
    return;
  }
  if (tid < 16)
    *(uint4*)(dstrow + (tid>>3)*(65*128) + (tid&7)*16) = z;   /* halo cols */
  int r = rp - 1;
  int col = tid & 63, cq = tid >> 6;
  const float* xb = x + (((size_t)(img*64 + cq*16)) << 12) + (r<<6) + col;
  union { u16 u[16]; uint4 v[2]; } pk;
  #pragma unroll
  for (int i = 0; i < 16; ++i)
    pk.u[i] = f2b(xb[((size_t)i) << 12]);
  char* dst = dstrow + (size_t)(col + 1)*128 + cq*32;
  *(uint4*)dst = pk.v[0];
  *(uint4*)(dst+16) = pk.v[1];
}

/* ---- channel stats from bf16 xp (36 MB read) ---- */
__global__ void k_stats(const char* __restrict__ xp, float* __restrict__ part){
  int img = blockIdx.x >> 2, rq = blockIdx.x & 3;
  int tid = threadIdx.x;
  int ch = tid & 7, cell0 = tid >> 3;
  float s[8], q[8];
  #pragma unroll
  for (int i = 0; i < 8; ++i){ s[i] = 0.f; q[i] = 0.f; }
  const char* base = xp + (size_t)img*IMG_BYTES + (size_t)(rq*16+1)*8448 + 128;
  for (int p = 0; p < 32; ++p){
    int cell = p*32 + cell0;
    int rr = cell >> 6, cc = cell & 63;
    uint4 v = *(const uint4*)(base + (size_t)rr*8448 + (size_t)cc*128 + ch*16);
    const u16* u = (const u16*)&v;
    #pragma unroll
    for (int i = 0; i < 8; ++i){
      float f = b2f(u[i]);
      s[i] += f; q[i] += f*f;
    }
  }
  #pragma unroll
  for (int i = 0; i < 8; ++i){
    #pragma unroll
    for (int off = 8; off < 64; off <<= 1){
      s[i] += __shfl_down(s[i], off);
      q[i] += __shfl_down(q[i], off);
    }
  }
  __shared__ float red[4][8][17];
  int w = tid >> 6, lane = tid & 63;
  if (lane < 8){
    #pragma unroll
    for (int i = 0; i < 8; ++i){
      red[w][lane][i]   = s[i];
      red[w][lane][8+i] = q[i];
    }
  }
  __syncthreads();
  if (tid < 128){
    int c = tid & 63, sq = tid >> 6;
    float acc = 0.f;
    #pragma unroll
    for (int wv = 0; wv < 4; ++wv)
      acc += red[wv][c>>3][sq*8 + (c&7)];
    part[(size_t)blockIdx.x*128 + sq*64 + c] = acc;
  }
}

/* ---- reduce 256 partial rows -> part2[128] ---- */
__global__ void k_red(const float* __restrict__ part, float* __restrict__ part2){
  int b = blockIdx.x;
  float s = part[(size_t)threadIdx.x*128 + b];
  #pragma unroll
  for (int off = 32; off; off >>= 1) s += __shfl_down(s, off);
  __shared__ float red[4];
  int w = threadIdx.x >> 6, lane = threadIdx.x & 63;
  if (lane == 0) red[w] = s;
  __syncthreads();
  if (threadIdx.x == 0) part2[b] = red[0]+red[1]+red[2]+red[3];
}

/* ---- BN finalize ---- */
__global__ void k_bnfin(const float* __restrict__ part2, const float* __restrict__ gamma,
                        const float* __restrict__ beta, float* __restrict__ scale,
                        float* __restrict__ shift){
  int c = threadIdx.x;
  const float inv = 1.f/262144.f;
  float mean = part2[c]*inv;
  float var  = part2[64+c]*inv - mean*mean;
  float sc = gamma[c] * rsqrtf(var + 1e-5f);
  scale[c] = sc;
  shift[c] = beta[c] - mean*sc;
}

/* ---- 9-class border bias, parallel: 192 blocks (o) x 64 thr (c) ---- */
__global__ void k_bias(const float* __restrict__ c1w, const float* __restrict__ c1b,
                       const float* __restrict__ shift, float* __restrict__ btab){
  int o = blockIdx.x, c = threadIdx.x;
  const float* wp = c1w + (o*64 + c)*9;
  float sh = shift[c];
  float tap[9];
  #pragma unroll
  for (int k = 0; k < 9; ++k) tap[k] = sh*wp[k];
  #pragma unroll
  for (int k = 0; k < 9; ++k){
    #pragma unroll
    for (int off = 32; off; off >>= 1)
      tap[k] += __shfl_down(tap[k], off);
  }
  if (c == 0){
    float b = c1b[o];
    #pragma unroll
    for (int cls = 0; cls < 9; ++cls){
      int rc = cls/3, cl = cls%3;
      int kh0 = (rc==0)?1:0, kh1 = (rc==2)?1:2;
      int kw0 = (cl==0)?1:0, kw1 = (cl==2)?1:2;
      float sm = b;
      for (int kh = kh0; kh <= kh1; ++kh)
        for (int kw = kw0; kw <= kw1; ++kw)
          sm += tap[kh*3+kw];
      btab[cls*192 + o] = sm;
    }
  }
}

/* ---- fused ConvLSTM step: ZERO LDS, ZERO barriers. 256 blocks =
        (n, row-pair, oh). 512 thr = 8 free-running waves (wr, og2, ch).
        A: global->register double-buffer (L2-broadcast). B: direct global
        reads (L1-resident via 9-tap reuse). ---- */
#define LOADA(BUF, v) do {                                                      \
  int vj_ = jp + (v)/9; if (vj_ >= 3) vj_ -= 3;                                 \
  int vt_ = tp + (v)%9; if (vt_ >= 9) vt_ -= 9;                                 \
  const char* ap_ = wA + ((size_t)((vj_*9 + vt_)*2 + oh))*12288                 \
                       + (og2<<10) + (lane<<4);                                 \
  BUF[0] = *(const short8*)(ap_);                                               \
  BUF[1] = *(const short8*)(ap_ + 2048);                                        \
  BUF[2] = *(const short8*)(ap_ + 4096);                                        \
  BUF[3] = *(const short8*)(ap_ + 6144);                                        \
  BUF[4] = *(const short8*)(ap_ + 8192);                                        \
  BUF[5] = *(const short8*)(ap_ + 10240);                                       \
} while(0)

#define COMPUTEG(BUF, v) do {                                                   \
  int vj_ = jp + (v)/9; if (vj_ >= 3) vj_ -= 3;                                 \
  int vt_ = tp + (v)%9; if (vt_ >= 9) vt_ -= 9;                                 \
  const int kh_ = vt_/3, kw_ = vt_ - kh_*3;                                     \
  const char* gbj_ = (vj_==0) ? gb0 : ((vj_==1) ? gb1 : gb2);                   \
  const char* bb_ = gbj_ + kh_*8448 + kw_*128 + broff;                          \
  _Pragma("unroll")                                                             \
  for (int cc = 0; cc < 2; ++cc){                                               \
    _Pragma("unroll")                                                           \
    for (int cf = 0; cf < 2; ++cf){                                             \
      short8 bf = *(const short8*)(bb_ + (cc<<6) + (cf<<11));                   \
      acc[0][cf] = __builtin_amdgcn_mfma_f32_16x16x32_bf16(BUF[cc*3+0], bf, acc[0][cf], 0,0,0); \
      acc[1][cf] = __builtin_amdgcn_mfma_f32_16x16x32_bf16(BUF[cc*3+1], bf, acc[1][cf], 0,0,0); \
      acc[2][cf] = __builtin_amdgcn_mfma_f32_16x16x32_bf16(BUF[cc*3+2], bf, acc[2][cf], 0,0,0); \
    }                                                                           \
  }                                                                             \
} while(0)

__global__ __launch_bounds__(512, 1) void k_step(
    const char* __restrict__ bnxp,
    const char* __restrict__ cpad_s, const char* __restrict__ hpad_s,
    char* __restrict__ cpad_d, char* __restrict__ hpad_d,
    const char* __restrict__ wA, const float* __restrict__ btab,
    float* __restrict__ cstate, float* __restrict__ out, int t)
{
  const int tid = threadIdx.x;
  const int w = tid >> 6, lane = tid & 63;
  const int l15 = lane & 15, l4 = lane >> 4;
  const int wr = w >> 2, og2 = (w >> 1) & 1, ch = w & 1;
  const int bid = blockIdx.x;
  const int oh = bid & 1, rp = (bid >> 1) & 31, n = bid >> 6;
  const int jp = bid % 3, tp = bid % 9;
  const int r = (rp << 1) + wr;

  /* wave's padded-row window base pointers (incl. wr offset) */
  const char* gb0 = bnxp   + (size_t)(t*4+n)*IMG_BYTES + rp*16896 + wr*8448;
  const char* gb1 = cpad_s + (size_t)n*IMG_BYTES + rp*16896 + wr*8448;
  const char* gb2 = hpad_s + (size_t)n*IMG_BYTES + rp*16896 + wr*8448;
  const int broff = ((ch<<5) + l15)*128 + (l4<<4);

  f32x4 acc[3][2];
  #pragma unroll
  for (int a = 0; a < 3; ++a)
    #pragma unroll
    for (int b = 0; b < 2; ++b)
      acc[a][b] = (f32x4){0.f,0.f,0.f,0.f};

  short8 a0[6], a1[6];
  LOADA(a0, 0);
  #pragma unroll
  for (int s = 0; s < 13; ++s){
    LOADA(a1, 2*s+1);
    COMPUTEG(a0, 2*s);
    LOADA(a0, 2*s+2);
    COMPUTEG(a1, 2*s+1);
  }
  COMPUTEG(a0, 26);

  /* epilogue: bias/cstate loaded HERE (keeps loop VGPR pressure low) */
  float* cslot = cstate + ((size_t)bid*512 + tid)*8;
  float cpv[8];
  if (t == 0){
    #pragma unroll
    for (int i = 0; i < 8; ++i) cpv[i] = 0.f;
  } else {
    f32x4 c0 = *(const f32x4*)cslot;
    f32x4 c1v = *(const f32x4*)(cslot + 4);
    cpv[0]=c0[0]; cpv[1]=c0[1]; cpv[2]=c0[2]; cpv[3]=c0[3];
    cpv[4]=c1v[0]; cpv[5]=c1v[1]; cpv[6]=c1v[2]; cpv[7]=c1v[3];
  }
  const int gc0 = ((oh<<1) + og2)*16 + l4*4;
  const int rc = (r==0) ? 0 : ((r==63) ? 2 : 1);
  const float* btr = btab + rc*576;

  const size_t ob = ((size_t)((t*4+n)*64)) << 12;
  char* hrow = hpad_d + (size_t)n*IMG_BYTES + (size_t)(r+1)*8448;
  char* crow = cpad_d + (size_t)n*IMG_BYTES + (size_t)(r+1)*8448;

  float cnew[8];
  #pragma unroll
  for (int cf = 0; cf < 2; ++cf){
    const int col = (ch<<5) + (cf<<4) + l15;
    const int p = (r<<6) + col;
    const int ccl = (col==0) ? 0 : ((col==63) ? 2 : 1);
    const float* bb = btr + ccl*192;
    union { u16 u[4]; uint2 v; } hp, cp2;
    #pragma unroll
    for (int reg = 0; reg < 4; ++reg){
      const int gc = gc0 + reg;
      float f  = sigm(acc[0][cf][reg] + bb[gc]);
      float og_ = sigm(acc[1][cf][reg] + bb[64+gc]);
      float g  = tanh_(acc[2][cf][reg] + bb[128+gc]);
      float cn = f*cpv[cf*4+reg] + (1.f-f)*g;
      float hn = og_ * tanh_(cn);
      cnew[cf*4+reg] = cn;
      out[ob + (((size_t)gc)<<12) + p] = hn;
      hp.u[reg]  = f2b(hn);
      cp2.u[reg] = f2b(cn);
    }
    *(uint2*)(hrow + (size_t)(col+1)*128 + gc0*2) = hp.v;
    *(uint2*)(crow + (size_t)(col+1)*128 + gc0*2) = cp2.v;
  }
  *(f32x4*)cslot       = (f32x4){cnew[0],cnew[1],cnew[2],cnew[3]};
  *(f32x4*)(cslot + 4) = (f32x4){cnew[4],cnew[5],cnew[6],cnew[7]};
}

extern "C" void kernel_launch(void* const* d_in, const int* in_sizes, int n_in,
                              void* d_out, int out_size, void* d_ws, size_t ws_size,
                              hipStream_t stream)
{
  (void)in_sizes; (void)n_in; (void)out_size; (void)ws_size;
  const float* x     = (const float*)d_in[0];
  const float* gamma = (const float*)d_in[1];
  const float* beta  = (const float*)d_in[2];
  const float* c1w   = (const float*)d_in[3];
  const float* c1b   = (const float*)d_in[4];
  const float* wh2h  = (const float*)d_in[5];
  const float* wc2h  = (const float*)d_in[6];
  char* ws  = (char*)d_ws;
  float* out = (float*)d_out;

  char* hpad0 = ws + WS_HC;
  char* cpad0 = ws + WS_HC + (size_t)4*IMG_BYTES;
  char* hpad1 = ws + WS_HC + (size_t)8*IMG_BYTES;
  char* cpad1 = ws + WS_HC + (size_t)12*IMG_BYTES;

  /* zero h/c ping-pong (halos + t0 state); cstate handled by t0 branch */
  hipMemsetAsync(ws + WS_HC, 0, (size_t)16*IMG_BYTES, stream);

  k_xt<<<4224, 256, 0, stream>>>(x, ws + WS_BNXP);
  k_stats<<<256, 256, 0, stream>>>(ws + WS_BNXP, (float*)(ws + WS_PARTB));
  k_red<<<128, 256, 0, stream>>>((const float*)(ws + WS_PARTB),
                                 (float*)(ws + WS_PART2));
  k_bnfin<<<1, 64, 0, stream>>>((const float*)(ws + WS_PART2), gamma, beta,
                                (float*)(ws + WS_SCALE), (float*)(ws + WS_SHIFT));
  k_wt<<<1296, 256, 0, stream>>>(c1w, wc2h, wh2h,
                                 (const float*)(ws + WS_SCALE), (u16*)(ws + WS_WA));
  k_bias<<<192, 64, 0, stream>>>(c1w, c1b, (const float*)(ws + WS_SHIFT),
                                 (float*)(ws + WS_BTAB));

  for (int t = 0; t < 16; ++t){
    const char* cs = (t & 1) ? cpad1 : cpad0;
    const char* hs = (t & 1) ? hpad1 : hpad0;
    char* cd = (t & 1) ? cpad0 : cpad1;
    char* hd = (t & 1) ? hpad0 : hpad1;
    k_step<<<256, 512, 0, stream>>>(ws + WS_BNXP, cs, hs, cd, hd,
                                    ws + WS_WA,
                                    (const float*)(ws + WS_BTAB),
                                    (float*)(ws + WS_CSTATE), out, t);
  }
}

// Round 19
// 349.907 us; speedup vs baseline: 1.9317x; 1.9317x over previous
//
#include <hip/hip_runtime.h>

typedef unsigned short u16;
typedef unsigned int   u32;
typedef __attribute__((ext_vector_type(8))) short short8;
typedef __attribute__((ext_vector_type(4))) float f32x4;

typedef __attribute__((address_space(1))) const void GASV;
typedef __attribute__((address_space(3))) void LASV;

#define IMG_BYTES  557568      /* 66*66*64*2 (padded bf16 image) */
#define WS_SCALE   0
#define WS_SHIFT   256
#define WS_BTAB    512                       /* 9*192*4 = 6912 B */
#define WS_PART2   7424                      /* 128*4 = 512 B */
#define WS_WA      8704                      /* 54 (27st x 2oh) * 12288 B */
#define WS_BNXP    672256                    /* 64 * IMG_BYTES */
#define WS_HC      (WS_BNXP + (size_t)64*IMG_BYTES)
#define WS_CSTATE  (WS_HC + (size_t)16*IMG_BYTES)    /* 4 MiB */
#define WS_PARTB   (WS_CSTATE + 4194304ULL)          /* 128 KiB */

/* k_step dynamic LDS: 4 input rows (66 cells x 128 B, XOR-swizzled chunks)
   + 6-deep weight ring */
#define SM_RING_OFF 33792                    /* 4 * 66 * 128 */
#define SMEM_TOT    (33792 + 6*12288)        /* 107520 B -> 1 block/CU */

__device__ __forceinline__ u16 f2b(float f){
  u32 x = __float_as_uint(f);
  return (u16)((x + 0x7fffu + ((x>>16)&1u)) >> 16);
}
__device__ __forceinline__ float b2f(u16 u){ return __uint_as_float(((u32)u)<<16); }
__device__ __forceinline__ float sigm(float x){ return 1.f/(1.f+__expf(-x)); }
__device__ __forceinline__ float tanh_(float x){
  float e = __expf(2.f*fabsf(x));
  float t = 1.f - 2.f/(e+1.f);
  return copysignf(t, x);
}

/* ---- weight transform: conv1 weights pre-scaled by BN scale[c] ---- */
__global__ void k_wt(const float* __restrict__ c1, const float* __restrict__ c2h,
                     const float* __restrict__ h2h, const float* __restrict__ scale,
                     u16* __restrict__ wA){
  int idx = blockIdx.x*256 + threadIdx.x;   /* 1296*256 = 331776 exact */
  int e = idx & 7;
  int lane = (idx >> 3) & 63;
  int v = idx >> 9;
  int f2 = v % 12;  v /= 12;
  int oh = v & 1;
  int stage = v >> 1;
  int cc = f2 / 6, gate = (f2 % 6) >> 1, og2 = f2 & 1;
  int j = stage / 9, tap = stage % 9;
  int och = gate*64 + (oh*2 + og2)*16 + (lane & 15);
  int c = cc*32 + (lane >> 4)*8 + e;
  const float* src = (j==0) ? c1 : ((j==1) ? c2h : h2h);
  float vv = src[(och*64 + c)*9 + tap];
  if (j == 0) vv *= scale[c];
  wA[idx] = f2b(vv);
}

/* ---- pure transpose: x f32 NCHW -> raw bf16 padded [img][66][66][64] ---- */
__global__ void k_xt(const float* __restrict__ x, char* __restrict__ xp){
  int img = blockIdx.x / 66, rp = blockIdx.x % 66;
  int tid = threadIdx.x;
  char* dstrow = xp + (size_t)img*IMG_BYTES + (size_t)rp*8448;
  const uint4 z = {0,0,0,0};
  if (rp == 0 || rp == 65){
    for (int i = tid; i < 528; i += 256) ((uint4*)dstrow)[i] = z;
    return;
  }
  if (tid < 16)
    *(uint4*)(dstrow + (tid>>3)*(65*128) + (tid&7)*16) = z;   /* halo cols */
  int r = rp - 1;
  int col = tid & 63, cq = tid >> 6;
  const float* xb = x + (((size_t)(img*64 + cq*16)) << 12) + (r<<6) + col;
  union { u16 u[16]; uint4 v[2]; } pk;
  #pragma unroll
  for (int i = 0; i < 16; ++i)
    pk.u[i] = f2b(xb[((size_t)i) << 12]);
  char* dst = dstrow + (size_t)(col + 1)*128 + cq*32;
  *(uint4*)dst = pk.v[0];
  *(uint4*)(dst+16) = pk.v[1];
}

/* ---- channel stats from bf16 xp (36 MB read) ---- */
__global__ void k_stats(const char* __restrict__ xp, float* __restrict__ part){
  int img = blockIdx.x >> 2, rq = blockIdx.x & 3;
  int tid = threadIdx.x;
  int ch = tid & 7, cell0 = tid >> 3;
  float s[8], q[8];
  #pragma unroll
  for (int i = 0; i < 8; ++i){ s[i] = 0.f; q[i] = 0.f; }
  const char* base = xp + (size_t)img*IMG_BYTES + (size_t)(rq*16+1)*8448 + 128;
  for (int p = 0; p < 32; ++p){
    int cell = p*32 + cell0;
    int rr = cell >> 6, cc = cell & 63;
    uint4 v = *(const uint4*)(base + (size_t)rr*8448 + (size_t)cc*128 + ch*16);
    const u16* u = (const u16*)&v;
    #pragma unroll
    for (int i = 0; i < 8; ++i){
      float f = b2f(u[i]);
      s[i] += f; q[i] += f*f;
    }
  }
  #pragma unroll
  for (int i = 0; i < 8; ++i){
    #pragma unroll
    for (int off = 8; off < 64; off <<= 1){
      s[i] += __shfl_down(s[i], off);
      q[i] += __shfl_down(q[i], off);
    }
  }
  __shared__ float red[4][8][17];
  int w = tid >> 6, lane = tid & 63;
  if (lane < 8){
    #pragma unroll
    for (int i = 0; i < 8; ++i){
      red[w][lane][i]   = s[i];
      red[w][lane][8+i] = q[i];
    }
  }
  __syncthreads();
  if (tid < 128){
    int c = tid & 63, sq = tid >> 6;
    float acc = 0.f;
    #pragma unroll
    for (int wv = 0; wv < 4; ++wv)
      acc += red[wv][c>>3][sq*8 + (c&7)];
    part[(size_t)blockIdx.x*128 + sq*64 + c] = acc;
  }
}

/* ---- reduce 256 partial rows -> part2[128] ---- */
__global__ void k_red(const float* __restrict__ part, float* __restrict__ part2){
  int b = blockIdx.x;
  float s = part[(size_t)threadIdx.x*128 + b];
  #pragma unroll
  for (int off = 32; off; off >>= 1) s += __shfl_down(s, off);
  __shared__ float red[4];
  int w = threadIdx.x >> 6, lane = threadIdx.x & 63;
  if (lane == 0) red[w] = s;
  __syncthreads();
  if (threadIdx.x == 0) part2[b] = red[0]+red[1]+red[2]+red[3];
}

/* ---- BN finalize ---- */
__global__ void k_bnfin(const float* __restrict__ part2, const float* __restrict__ gamma,
                        const float* __restrict__ beta, float* __restrict__ scale,
                        float* __restrict__ shift){
  int c = threadIdx.x;
  const float inv = 1.f/262144.f;
  float mean = part2[c]*inv;
  float var  = part2[64+c]*inv - mean*mean;
  float sc = gamma[c] * rsqrtf(var + 1e-5f);
  scale[c] = sc;
  shift[c] = beta[c] - mean*sc;
}

/* ---- 9-class border bias, parallel: 192 blocks (o) x 64 thr (c) ---- */
__global__ void k_bias(const float* __restrict__ c1w, const float* __restrict__ c1b,
                       const float* __restrict__ shift, float* __restrict__ btab){
  int o = blockIdx.x, c = threadIdx.x;
  const float* wp = c1w + (o*64 + c)*9;
  float sh = shift[c];
  float tap[9];
  #pragma unroll
  for (int k = 0; k < 9; ++k) tap[k] = sh*wp[k];
  #pragma unroll
  for (int k = 0; k < 9; ++k){
    #pragma unroll
    for (int off = 32; off; off >>= 1)
      tap[k] += __shfl_down(tap[k], off);
  }
  if (c == 0){
    float b = c1b[o];
    #pragma unroll
    for (int cls = 0; cls < 9; ++cls){
      int rc = cls/3, cl = cls%3;
      int kh0 = (rc==0)?1:0, kh1 = (rc==2)?1:2;
      int kw0 = (cl==0)?1:0, kw1 = (cl==2)?1:2;
      float sm = b;
      for (int kh = kh0; kh <= kh1; ++kh)
        for (int kw = kw0; kw <= kw1; ++kw)
          sm += tap[kh*3+kw];
      btab[cls*192 + o] = sm;
    }
  }
}

/* ---- fused ConvLSTM step (R15/R17 structure — best known) ---- */
#define STAGE_W(v) do {                                                         \
  if ((v) <= 26 && w < 4){                                                      \
    int _vj = jp + (v)/9; if (_vj >= 3) _vj -= 3;                               \
    int _vt = tp + (v)%9; if (_vt >= 9) _vt -= 9;                               \
    const char* _gs = wA + ((size_t)((_vj*9 + _vt)*2 + oh))*12288               \
                        + w*3072 + lane*16;                                     \
    char* _ls = smem + SM_RING_OFF + ((v)%6)*12288 + w*3072;                    \
    __builtin_amdgcn_global_load_lds((GASV*)(_gs),        (LASV*)(_ls),        16, 0, 0); \
    __builtin_amdgcn_global_load_lds((GASV*)(_gs + 1024), (LASV*)(_ls + 1024), 16, 0, 0); \
    __builtin_amdgcn_global_load_lds((GASV*)(_gs + 2048), (LASV*)(_ls + 2048), 16, 0, 0); \
  }                                                                             \
} while(0)

#define WAITN_BAR(N) do {                                                       \
  asm volatile("s_waitcnt vmcnt(" #N ")\n\ts_barrier" ::: "memory");            \
  __builtin_amdgcn_sched_barrier(0);                                            \
} while(0)

#define COMPUTE(u) do {                                                         \
  int tv = tp + (u)%9; if (tv >= 9) tv -= 9;                                    \
  const int kh = tv/3, kw = tv - kh*3;                                          \
  const char* ab0 = smem + SM_RING_OFF + ((u)%6)*12288 + og2*1024 + lane*16;    \
  const int c_ = (ch<<5) + kw + l15;                                            \
  const char* rowb = smem + (wr + kh)*8448 + c_*128;                            \
  _Pragma("unroll")                                                             \
  for (int cc = 0; cc < 2; ++cc){                                               \
    short8 af = *(const short8*)(ab0 + cc*6144);                                \
    short8 ao = *(const short8*)(ab0 + cc*6144 + 2048);                         \
    short8 ag = *(const short8*)(ab0 + cc*6144 + 4096);                         \
    const char* ib0 = rowb + ((((cc<<2)|l4) ^ (c_&7))<<4);                      \
    _Pragma("unroll")                                                           \
    for (int cf = 0; cf < 2; ++cf){                                             \
      short8 bf = *(const short8*)(ib0 + (cf<<11));                             \
      acc[0][cf] = __builtin_amdgcn_mfma_f32_16x16x32_bf16(af, bf, acc[0][cf], 0,0,0); \
      acc[1][cf] = __builtin_amdgcn_mfma_f32_16x16x32_bf16(ao, bf, acc[1][cf], 0,0,0); \
      acc[2][cf] = __builtin_amdgcn_mfma_f32_16x16x32_bf16(ag, bf, acc[2][cf], 0,0,0); \
    }                                                                           \
  }                                                                             \
} while(0)

__global__ __launch_bounds__(512, 1) void k_step(
    const char* __restrict__ bnxp,
    const char* __restrict__ cpad_s, const char* __restrict__ hpad_s,
    char* __restrict__ cpad_d, char* __restrict__ hpad_d,
    const char* __restrict__ wA, const float* __restrict__ btab,
    float* __restrict__ cstate, float* __restrict__ out, int t)
{
  extern __shared__ __align__(16) char smem[];
  const int tid = threadIdx.x;
  const int w = tid >> 6, lane = tid & 63;
  const int l15 = lane & 15, l4 = lane >> 4;
  const int wr = w >> 2, og2 = (w >> 1) & 1, ch = w & 1;
  const int bid = blockIdx.x;
  const int oh = bid & 1, rp = (bid >> 1) & 31, n = bid >> 6;
  const int jp = bid % 3, tp = bid % 9;
  const int r = (rp << 1) + wr;

  const char* gb0 = bnxp   + (size_t)(t*4+n)*IMG_BYTES + rp*16896;
  const char* gb1 = cpad_s + (size_t)n*IMG_BYTES + rp*16896;
  const char* gb2 = hpad_s + (size_t)n*IMG_BYTES + rp*16896;

  /* cstate: coalesced [bid][tid][8] f32; t==0 -> zeros (skip poison read) */
  float* cslot = cstate + ((size_t)bid*512 + tid)*8;
  float cpv[8];
  if (t == 0){
    #pragma unroll
    for (int i = 0; i < 8; ++i) cpv[i] = 0.f;
  } else {
    f32x4 c0 = *(const f32x4*)cslot;
    f32x4 c1v = *(const f32x4*)(cslot + 4);
    cpv[0]=c0[0]; cpv[1]=c0[1]; cpv[2]=c0[2]; cpv[3]=c0[3];
    cpv[4]=c1v[0]; cpv[5]=c1v[1]; cpv[6]=c1v[2]; cpv[7]=c1v[3];
  }

  const int gc0 = ((oh<<1) + og2)*16 + l4*4;
  const int rc = (r==0) ? 0 : ((r==63) ? 2 : 1);
  const float* btr = btab + rc*576;
  float bv2[2][12];
  #pragma unroll
  for (int cf = 0; cf < 2; ++cf){
    const int col = (ch<<5) + (cf<<4) + l15;
    const int ccl = (col==0) ? 0 : ((col==63) ? 2 : 1);
    const float* bb = btr + ccl*192;
    #pragma unroll
    for (int reg = 0; reg < 4; ++reg){
      bv2[cf][reg]   = bb[gc0+reg];
      bv2[cf][4+reg] = bb[64+gc0+reg];
      bv2[cf][8+reg] = bb[128+gc0+reg];
    }
  }

  f32x4 acc[3][2];
  #pragma unroll
  for (int a = 0; a < 3; ++a)
    #pragma unroll
    for (int b = 0; b < 2; ++b)
      acc[a][b] = (f32x4){0.f,0.f,0.f,0.f};

  STAGE_W(0); STAGE_W(1); STAGE_W(2); STAGE_W(3);

  #pragma unroll
  for (int jj = 0; jj < 3; ++jj){
    int jv = jp + jj; if (jv >= 3) jv -= 3;
    const char* gbj = (jv==0) ? gb0 : ((jv==1) ? gb1 : gb2);
    for (int i = tid; i < 2112; i += 512){
      int rr = i / 528;
      int iw = i - rr*528;
      int c = iw >> 3, k = iw & 7;
      *(uint4*)(smem + rr*8448 + c*128 + ((k ^ (c&7))<<4)) =
          *(const uint4*)(gbj + rr*8448 + iw*16);
    }
    __syncthreads();

    #pragma unroll
    for (int pp = 0; pp < 4; ++pp){
      const int u = jj*9 + 2*pp;
      STAGE_W(u+4); STAGE_W(u+5);
      __builtin_amdgcn_s_setprio(1);
      COMPUTE(u);
      COMPUTE(u+1);
      __builtin_amdgcn_s_setprio(0);
      if (u == 22)      WAITN_BAR(3);
      else if (u == 24) WAITN_BAR(0);
      else              WAITN_BAR(6);
    }
    {
      const int u = jj*9 + 8;
      STAGE_W(u+4);
      __builtin_amdgcn_s_setprio(1);
      COMPUTE(u);
      __builtin_amdgcn_s_setprio(0);
    }
  }

  /* epilogue: gates; nontemporal out stores (never re-read -> keep L2 for
     weights/pads); coalesced cstate write; bf16 h/c pad writes */
  const size_t ob = ((size_t)((t*4+n)*64)) << 12;
  char* hrow = hpad_d + (size_t)n*IMG_BYTES + (size_t)(r+1)*8448;
  char* crow = cpad_d + (size_t)n*IMG_BYTES + (size_t)(r+1)*8448;

  float cnew[8];
  #pragma unroll
  for (int cf = 0; cf < 2; ++cf){
    const int col = (ch<<5) + (cf<<4) + l15;
    const int p = (r<<6) + col;
    union { u16 u[4]; uint2 v; } hp, cp2;
    #pragma unroll
    for (int reg = 0; reg < 4; ++reg){
      const int gc = gc0 + reg;
      float f  = sigm(acc[0][cf][reg] + bv2[cf][reg]);
      float og_ = sigm(acc[1][cf][reg] + bv2[cf][4+reg]);
      float g  = tanh_(acc[2][cf][reg] + bv2[cf][8+reg]);
      float cn = f*cpv[cf*4+reg] + (1.f-f)*g;
      float hn = og_ * tanh_(cn);
      cnew[cf*4+reg] = cn;
      __builtin_nontemporal_store(hn, out + ob + (((size_t)gc)<<12) + p);
      hp.u[reg]  = f2b(hn);
      cp2.u[reg] = f2b(cn);
    }
    *(uint2*)(hrow + (size_t)(col+1)*128 + gc0*2) = hp.v;
    *(uint2*)(crow + (size_t)(col+1)*128 + gc0*2) = cp2.v;
  }
  *(f32x4*)cslot       = (f32x4){cnew[0],cnew[1],cnew[2],cnew[3]};
  *(f32x4*)(cslot + 4) = (f32x4){cnew[4],cnew[5],cnew[6],cnew[7]};
}

extern "C" void kernel_launch(void* const* d_in, const int* in_sizes, int n_in,
                              void* d_out, int out_size, void* d_ws, size_t ws_size,
                              hipStream_t stream)
{
  (void)in_sizes; (void)n_in; (void)out_size; (void)ws_size;
  const float* x     = (const float*)d_in[0];
  const float* gamma = (const float*)d_in[1];
  const float* beta  = (const float*)d_in[2];
  const float* c1w   = (const float*)d_in[3];
  const float* c1b   = (const float*)d_in[4];
  const float* wh2h  = (const float*)d_in[5];
  const float* wc2h  = (const float*)d_in[6];
  char* ws  = (char*)d_ws;
  float* out = (float*)d_out;

  hipFuncSetAttribute(reinterpret_cast<const void*>(k_step),
                      hipFuncAttributeMaxDynamicSharedMemorySize, SMEM_TOT);

  char* hpad0 = ws + WS_HC;
  char* cpad0 = ws + WS_HC + (size_t)4*IMG_BYTES;
  char* hpad1 = ws + WS_HC + (size_t)8*IMG_BYTES;
  char* cpad1 = ws + WS_HC + (size_t)12*IMG_BYTES;

  /* zero h/c ping-pong (halos + t0 state); cstate handled by t0 branch */
  hipMemsetAsync(ws + WS_HC, 0, (size_t)16*IMG_BYTES, stream);

  k_xt<<<4224, 256, 0, stream>>>(x, ws + WS_BNXP);
  k_stats<<<256, 256, 0, stream>>>(ws + WS_BNXP, (float*)(ws + WS_PARTB));
  k_red<<<128, 256, 0, stream>>>((const float*)(ws + WS_PARTB),
                                 (float*)(ws + WS_PART2));
  k_bnfin<<<1, 64, 0, stream>>>((const float*)(ws + WS_PART2), gamma, beta,
                                (float*)(ws + WS_SCALE), (float*)(ws + WS_SHIFT));
  k_wt<<<1296, 256, 0, stream>>>(c1w, wc2h, wh2h,
                                 (const float*)(ws + WS_SCALE), (u16*)(ws + WS_WA));
  k_bias<<<192, 64, 0, stream>>>(c1w, c1b, (const float*)(ws + WS_SHIFT),
                                 (float*)(ws + WS_BTAB));

  for (int t = 0; t < 16; ++t){
    const char* cs = (t & 1) ? cpad1 : cpad0;
    const char* hs = (t & 1) ? hpad1 : hpad0;
    char* cd = (t & 1) ? cpad0 : cpad1;
    char* hd = (t & 1) ? hpad0 : hpad1;
    k_step<<<256, 512, SMEM_TOT, stream>>>(ws + WS_BNXP, cs, hs, cd, hd,
                                           ws + WS_WA,
                                           (const float*)(ws + WS_BTAB),
                                           (float*)(ws + WS_CSTATE), out, t);
  }
}

// Round 20
// 344.733 us; speedup vs baseline: 1.9607x; 1.0150x over previous
//
#include <hip/hip_runtime.h>

typedef unsigned short u16;
typedef unsigned int   u32;
typedef __attribute__((ext_vector_type(8))) short short8;
typedef __attribute__((ext_vector_type(4))) float f32x4;

typedef __attribute__((address_space(1))) const void GASV;
typedef __attribute__((address_space(3))) void LASV;

#define IMG_BYTES  557568      /* 66*66*64*2 (padded bf16 image) */
#define WS_SCALE   0
#define WS_SHIFT   256
#define WS_BTAB    512                       /* 9*192*4 = 6912 B */
#define WS_PART2   7424                      /* 128*4 = 512 B */
#define WS_WA      8704                      /* 54 (27st x 2oh) * 12288 B */
#define WS_BNXP    672256                    /* 64 * IMG_BYTES */
#define WS_HC      (WS_BNXP + (size_t)64*IMG_BYTES)
#define WS_CSTATE  (WS_HC + (size_t)16*IMG_BYTES)    /* 4 MiB */
#define WS_PARTB   (WS_CSTATE + 4194304ULL)          /* 128 KiB */

/* k_step dynamic LDS: 4 input rows (66 cells x 128 B, XOR-swizzled chunks)
   + 6-deep weight ring */
#define SM_RING_OFF 33792                    /* 4 * 66 * 128 */
#define SMEM_TOT    (33792 + 6*12288)        /* 107520 B -> 1 block/CU */

__device__ __forceinline__ u16 f2b(float f){
  u32 x = __float_as_uint(f);
  return (u16)((x + 0x7fffu + ((x>>16)&1u)) >> 16);
}
__device__ __forceinline__ float b2f(u16 u){ return __uint_as_float(((u32)u)<<16); }
__device__ __forceinline__ float sigm(float x){ return 1.f/(1.f+__expf(-x)); }
__device__ __forceinline__ float tanh_(float x){
  float e = __expf(2.f*fabsf(x));
  float t = 1.f - 2.f/(e+1.f);
  return copysignf(t, x);
}

/* ---- weight transform: conv1 weights pre-scaled by BN scale[c] ---- */
__global__ void k_wt(const float* __restrict__ c1, const float* __restrict__ c2h,
                     const float* __restrict__ h2h, const float* __restrict__ scale,
                     u16* __restrict__ wA){
  int idx = blockIdx.x*256 + threadIdx.x;   /* 1296*256 = 331776 exact */
  int e = idx & 7;
  int lane = (idx >> 3) & 63;
  int v = idx >> 9;
  int f2 = v % 12;  v /= 12;
  int oh = v & 1;
  int stage = v >> 1;
  int cc = f2 / 6, gate = (f2 % 6) >> 1, og2 = f2 & 1;
  int j = stage / 9, tap = stage % 9;
  int och = gate*64 + (oh*2 + og2)*16 + (lane & 15);
  int c = cc*32 + (lane >> 4)*8 + e;
  const float* src = (j==0) ? c1 : ((j==1) ? c2h : h2h);
  float vv = src[(och*64 + c)*9 + tap];
  if (j == 0) vv *= scale[c];
  wA[idx] = f2b(vv);
}

/* ---- pure transpose: x f32 NCHW -> raw bf16 padded [img][66][66][64] ---- */
__global__ void k_xt(const float* __restrict__ x, char* __restrict__ xp){
  int img = blockIdx.x / 66, rp = blockIdx.x % 66;
  int tid = threadIdx.x;
  char* dstrow = xp + (size_t)img*IMG_BYTES + (size_t)rp*8448;
  const uint4 z = {0,0,0,0};
  if (rp == 0 || rp == 65){
    for (int i = tid; i < 528; i += 256) ((uint4*)dstrow)[i] = z;
    return;
  }
  if (tid < 16)
    *(uint4*)(dstrow + (tid>>3)*(65*128) + (tid&7)*16) = z;   /* halo cols */
  int r = rp - 1;
  int col = tid & 63, cq = tid >> 6;
  const float* xb = x + (((size_t)(img*64 + cq*16)) << 12) + (r<<6) + col;
  union { u16 u[16]; uint4 v[2]; } pk;
  #pragma unroll
  for (int i = 0; i < 16; ++i)
    pk.u[i] = f2b(xb[((size_t)i) << 12]);
  char* dst = dstrow + (size_t)(col + 1)*128 + cq*32;
  *(uint4*)dst = pk.v[0];
  *(uint4*)(dst+16) = pk.v[1];
}

/* ---- channel stats from bf16 xp (36 MB read) ---- */
__global__ void k_stats(const char* __restrict__ xp, float* __restrict__ part){
  int img = blockIdx.x >> 2, rq = blockIdx.x & 3;
  int tid = threadIdx.x;
  int ch = tid & 7, cell0 = tid >> 3;
  float s[8], q[8];
  #pragma unroll
  for (int i = 0; i < 8; ++i){ s[i] = 0.f; q[i] = 0.f; }
  const char* base = xp + (size_t)img*IMG_BYTES + (size_t)(rq*16+1)*8448 + 128;
  for (int p = 0; p < 32; ++p){
    int cell = p*32 + cell0;
    int rr = cell >> 6, cc = cell & 63;
    uint4 v = *(const uint4*)(base + (size_t)rr*8448 + (size_t)cc*128 + ch*16);
    const u16* u = (const u16*)&v;
    #pragma unroll
    for (int i = 0; i < 8; ++i){
      float f = b2f(u[i]);
      s[i] += f; q[i] += f*f;
    }
  }
  #pragma unroll
  for (int i = 0; i < 8; ++i){
    #pragma unroll
    for (int off = 8; off < 64; off <<= 1){
      s[i] += __shfl_down(s[i], off);
      q[i] += __shfl_down(q[i], off);
    }
  }
  __shared__ float red[4][8][17];
  int w = tid >> 6, lane = tid & 63;
  if (lane < 8){
    #pragma unroll
    for (int i = 0; i < 8; ++i){
      red[w][lane][i]   = s[i];
      red[w][lane][8+i] = q[i];
    }
  }
  __syncthreads();
  if (tid < 128){
    int c = tid & 63, sq = tid >> 6;
    float acc = 0.f;
    #pragma unroll
    for (int wv = 0; wv < 4; ++wv)
      acc += red[wv][c>>3][sq*8 + (c&7)];
    part[(size_t)blockIdx.x*128 + sq*64 + c] = acc;
  }
}

/* ---- reduce 256 partial rows -> part2[128] ---- */
__global__ void k_red(const float* __restrict__ part, float* __restrict__ part2){
  int b = blockIdx.x;
  float s = part[(size_t)threadIdx.x*128 + b];
  #pragma unroll
  for (int off = 32; off; off >>= 1) s += __shfl_down(s, off);
  __shared__ float red[4];
  int w = threadIdx.x >> 6, lane = threadIdx.x & 63;
  if (lane == 0) red[w] = s;
  __syncthreads();
  if (threadIdx.x == 0) part2[b] = red[0]+red[1]+red[2]+red[3];
}

/* ---- BN finalize ---- */
__global__ void k_bnfin(const float* __restrict__ part2, const float* __restrict__ gamma,
                        const float* __restrict__ beta, float* __restrict__ scale,
                        float* __restrict__ shift){
  int c = threadIdx.x;
  const float inv = 1.f/262144.f;
  float mean = part2[c]*inv;
  float var  = part2[64+c]*inv - mean*mean;
  float sc = gamma[c] * rsqrtf(var + 1e-5f);
  scale[c] = sc;
  shift[c] = beta[c] - mean*sc;
}

/* ---- 9-class border bias, parallel: 192 blocks (o) x 64 thr (c) ---- */
__global__ void k_bias(const float* __restrict__ c1w, const float* __restrict__ c1b,
                       const float* __restrict__ shift, float* __restrict__ btab){
  int o = blockIdx.x, c = threadIdx.x;
  const float* wp = c1w + (o*64 + c)*9;
  float sh = shift[c];
  float tap[9];
  #pragma unroll
  for (int k = 0; k < 9; ++k) tap[k] = sh*wp[k];
  #pragma unroll
  for (int k = 0; k < 9; ++k){
    #pragma unroll
    for (int off = 32; off; off >>= 1)
      tap[k] += __shfl_down(tap[k], off);
  }
  if (c == 0){
    float b = c1b[o];
    #pragma unroll
    for (int cls = 0; cls < 9; ++cls){
      int rc = cls/3, cl = cls%3;
      int kh0 = (rc==0)?1:0, kh1 = (rc==2)?1:2;
      int kw0 = (cl==0)?1:0, kw1 = (cl==2)?1:2;
      float sm = b;
      for (int kh = kh0; kh <= kh1; ++kh)
        for (int kw = kw0; kw <= kw1; ++kw)
          sm += tap[kh*3+kw];
      btab[cls*192 + o] = sm;
    }
  }
}

/* ---- fused ConvLSTM step (R19 structure + t==0 conv1-only fast path) ---- */
#define STAGE_W(v) do {                                                         \
  if ((v) <= 26 && w < 4){                                                      \
    int _vj = jp + (v)/9; if (_vj >= 3) _vj -= 3;                               \
    int _vt = tp + (v)%9; if (_vt >= 9) _vt -= 9;                               \
    const char* _gs = wA + ((size_t)((_vj*9 + _vt)*2 + oh))*12288               \
                        + w*3072 + lane*16;                                     \
    char* _ls = smem + SM_RING_OFF + ((v)%6)*12288 + w*3072;                    \
    __builtin_amdgcn_global_load_lds((GASV*)(_gs),        (LASV*)(_ls),        16, 0, 0); \
    __builtin_amdgcn_global_load_lds((GASV*)(_gs + 1024), (LASV*)(_ls + 1024), 16, 0, 0); \
    __builtin_amdgcn_global_load_lds((GASV*)(_gs + 2048), (LASV*)(_ls + 2048), 16, 0, 0); \
  }                                                                             \
} while(0)

/* t==0 variant: conv1 only (jv fixed 0), stages 0..8 */
#define STAGE_W0(v) do {                                                        \
  if ((v) <= 8 && w < 4){                                                       \
    int _vt = tp + (v)%9; if (_vt >= 9) _vt -= 9;                               \
    const char* _gs = wA + ((size_t)(_vt*2 + oh))*12288 + w*3072 + lane*16;     \
    char* _ls = smem + SM_RING_OFF + ((v)%6)*12288 + w*3072;                    \
    __builtin_amdgcn_global_load_lds((GASV*)(_gs),        (LASV*)(_ls),        16, 0, 0); \
    __builtin_amdgcn_global_load_lds((GASV*)(_gs + 1024), (LASV*)(_ls + 1024), 16, 0, 0); \
    __builtin_amdgcn_global_load_lds((GASV*)(_gs + 2048), (LASV*)(_ls + 2048), 16, 0, 0); \
  }                                                                             \
} while(0)

#define WAITN_BAR(N) do {                                                       \
  asm volatile("s_waitcnt vmcnt(" #N ")\n\ts_barrier" ::: "memory");            \
  __builtin_amdgcn_sched_barrier(0);                                            \
} while(0)

#define COMPUTE(u) do {                                                         \
  int tv = tp + (u)%9; if (tv >= 9) tv -= 9;                                    \
  const int kh = tv/3, kw = tv - kh*3;                                          \
  const char* ab0 = smem + SM_RING_OFF + ((u)%6)*12288 + og2*1024 + lane*16;    \
  const int c_ = (ch<<5) + kw + l15;                                            \
  const char* rowb = smem + (wr + kh)*8448 + c_*128;                            \
  _Pragma("unroll")                                                             \
  for (int cc = 0; cc < 2; ++cc){                                               \
    short8 af = *(const short8*)(ab0 + cc*6144);                                \
    short8 ao = *(const short8*)(ab0 + cc*6144 + 2048);                         \
    short8 ag = *(const short8*)(ab0 + cc*6144 + 4096);                         \
    const char* ib0 = rowb + ((((cc<<2)|l4) ^ (c_&7))<<4);                      \
    _Pragma("unroll")                                                           \
    for (int cf = 0; cf < 2; ++cf){                                             \
      short8 bf = *(const short8*)(ib0 + (cf<<11));                             \
      acc[0][cf] = __builtin_amdgcn_mfma_f32_16x16x32_bf16(af, bf, acc[0][cf], 0,0,0); \
      acc[1][cf] = __builtin_amdgcn_mfma_f32_16x16x32_bf16(ao, bf, acc[1][cf], 0,0,0); \
      acc[2][cf] = __builtin_amdgcn_mfma_f32_16x16x32_bf16(ag, bf, acc[2][cf], 0,0,0); \
    }                                                                           \
  }                                                                             \
} while(0)

__global__ __launch_bounds__(512, 1) void k_step(
    const char* __restrict__ bnxp,
    const char* __restrict__ cpad_s, const char* __restrict__ hpad_s,
    char* __restrict__ cpad_d, char* __restrict__ hpad_d,
    const char* __restrict__ wA, const float* __restrict__ btab,
    float* __restrict__ cstate, float* __restrict__ out, int t)
{
  extern __shared__ __align__(16) char smem[];
  const int tid = threadIdx.x;
  const int w = tid >> 6, lane = tid & 63;
  const int l15 = lane & 15, l4 = lane >> 4;
  const int wr = w >> 2, og2 = (w >> 1) & 1, ch = w & 1;
  const int bid = blockIdx.x;
  const int oh = bid & 1, rp = (bid >> 1) & 31, n = bid >> 6;
  const int jp = bid % 3, tp = bid % 9;
  const int r = (rp << 1) + wr;

  const char* gb0 = bnxp   + (size_t)(t*4+n)*IMG_BYTES + rp*16896;
  const char* gb1 = cpad_s + (size_t)n*IMG_BYTES + rp*16896;
  const char* gb2 = hpad_s + (size_t)n*IMG_BYTES + rp*16896;

  /* cstate: coalesced [bid][tid][8] f32; t==0 -> zeros (skip poison read) */
  float* cslot = cstate + ((size_t)bid*512 + tid)*8;
  float cpv[8];
  if (t == 0){
    #pragma unroll
    for (int i = 0; i < 8; ++i) cpv[i] = 0.f;
  } else {
    f32x4 c0 = *(const f32x4*)cslot;
    f32x4 c1v = *(const f32x4*)(cslot + 4);
    cpv[0]=c0[0]; cpv[1]=c0[1]; cpv[2]=c0[2]; cpv[3]=c0[3];
    cpv[4]=c1v[0]; cpv[5]=c1v[1]; cpv[6]=c1v[2]; cpv[7]=c1v[3];
  }

  const int gc0 = ((oh<<1) + og2)*16 + l4*4;
  const int rc = (r==0) ? 0 : ((r==63) ? 2 : 1);
  const float* btr = btab + rc*576;
  float bv2[2][12];
  #pragma unroll
  for (int cf = 0; cf < 2; ++cf){
    const int col = (ch<<5) + (cf<<4) + l15;
    const int ccl = (col==0) ? 0 : ((col==63) ? 2 : 1);
    const float* bb = btr + ccl*192;
    #pragma unroll
    for (int reg = 0; reg < 4; ++reg){
      bv2[cf][reg]   = bb[gc0+reg];
      bv2[cf][4+reg] = bb[64+gc0+reg];
      bv2[cf][8+reg] = bb[128+gc0+reg];
    }
  }

  f32x4 acc[3][2];
  #pragma unroll
  for (int a = 0; a < 3; ++a)
    #pragma unroll
    for (int b = 0; b < 2; ++b)
      acc[a][b] = (f32x4){0.f,0.f,0.f,0.f};

  if (t == 0){
    /* ---- fast path: h=c=0, only conv1's 9 stages ---- */
    STAGE_W0(0); STAGE_W0(1); STAGE_W0(2); STAGE_W0(3);
    for (int i = tid; i < 2112; i += 512){
      int rr = i / 528;
      int iw = i - rr*528;
      int c = iw >> 3, k = iw & 7;
      *(uint4*)(smem + rr*8448 + c*128 + ((k ^ (c&7))<<4)) =
          *(const uint4*)(gb0 + rr*8448 + iw*16);
    }
    __syncthreads();   /* drains prologue stages too */

    #pragma unroll
    for (int pp = 0; pp < 4; ++pp){
      const int u = 2*pp;
      STAGE_W0(u+4); STAGE_W0(u+5);
      __builtin_amdgcn_s_setprio(1);
      COMPUTE(u);
      COMPUTE(u+1);
      __builtin_amdgcn_s_setprio(0);
      if (u == 4)      WAITN_BAR(3);
      else if (u == 6) WAITN_BAR(0);
      else             WAITN_BAR(6);
    }
    __builtin_amdgcn_s_setprio(1);
    COMPUTE(8);
    __builtin_amdgcn_s_setprio(0);
  } else {
    /* ---- full path: 27 stages over conv1/c2h/h2h (jp-rotated) ---- */
    STAGE_W(0); STAGE_W(1); STAGE_W(2); STAGE_W(3);

    #pragma unroll
    for (int jj = 0; jj < 3; ++jj){
      int jv = jp + jj; if (jv >= 3) jv -= 3;
      const char* gbj = (jv==0) ? gb0 : ((jv==1) ? gb1 : gb2);
      for (int i = tid; i < 2112; i += 512){
        int rr = i / 528;
        int iw = i - rr*528;
        int c = iw >> 3, k = iw & 7;
        *(uint4*)(smem + rr*8448 + c*128 + ((k ^ (c&7))<<4)) =
            *(const uint4*)(gbj + rr*8448 + iw*16);
      }
      __syncthreads();

      #pragma unroll
      for (int pp = 0; pp < 4; ++pp){
        const int u = jj*9 + 2*pp;
        STAGE_W(u+4); STAGE_W(u+5);
        __builtin_amdgcn_s_setprio(1);
        COMPUTE(u);
        COMPUTE(u+1);
        __builtin_amdgcn_s_setprio(0);
        if (u == 22)      WAITN_BAR(3);
        else if (u == 24) WAITN_BAR(0);
        else              WAITN_BAR(6);
      }
      {
        const int u = jj*9 + 8;
        STAGE_W(u+4);
        __builtin_amdgcn_s_setprio(1);
        COMPUTE(u);
        __builtin_amdgcn_s_setprio(0);
      }
    }
  }

  /* epilogue: gates; nontemporal out stores; coalesced cstate write;
     bf16 h/c pad writes */
  const size_t ob = ((size_t)((t*4+n)*64)) << 12;
  char* hrow = hpad_d + (size_t)n*IMG_BYTES + (size_t)(r+1)*8448;
  char* crow = cpad_d + (size_t)n*IMG_BYTES + (size_t)(r+1)*8448;

  float cnew[8];
  #pragma unroll
  for (int cf = 0; cf < 2; ++cf){
    const int col = (ch<<5) + (cf<<4) + l15;
    const int p = (r<<6) + col;
    union { u16 u[4]; uint2 v; } hp, cp2;
    #pragma unroll
    for (int reg = 0; reg < 4; ++reg){
      const int gc = gc0 + reg;
      float f  = sigm(acc[0][cf][reg] + bv2[cf][reg]);
      float og_ = sigm(acc[1][cf][reg] + bv2[cf][4+reg]);
      float g  = tanh_(acc[2][cf][reg] + bv2[cf][8+reg]);
      float cn = f*cpv[cf*4+reg] + (1.f-f)*g;
      float hn = og_ * tanh_(cn);
      cnew[cf*4+reg] = cn;
      __builtin_nontemporal_store(hn, out + ob + (((size_t)gc)<<12) + p);
      hp.u[reg]  = f2b(hn);
      cp2.u[reg] = f2b(cn);
    }
    *(uint2*)(hrow + (size_t)(col+1)*128 + gc0*2) = hp.v;
    *(uint2*)(crow + (size_t)(col+1)*128 + gc0*2) = cp2.v;
  }
  *(f32x4*)cslot       = (f32x4){cnew[0],cnew[1],cnew[2],cnew[3]};
  *(f32x4*)(cslot + 4) = (f32x4){cnew[4],cnew[5],cnew[6],cnew[7]};
}

extern "C" void kernel_launch(void* const* d_in, const int* in_sizes, int n_in,
                              void* d_out, int out_size, void* d_ws, size_t ws_size,
                              hipStream_t stream)
{
  (void)in_sizes; (void)n_in; (void)out_size; (void)ws_size;
  const float* x     = (const float*)d_in[0];
  const float* gamma = (const float*)d_in[1];
  const float* beta  = (const float*)d_in[2];
  const float* c1w   = (const float*)d_in[3];
  const float* c1b   = (const float*)d_in[4];
  const float* wh2h  = (const float*)d_in[5];
  const float* wc2h  = (const float*)d_in[6];
  char* ws  = (char*)d_ws;
  float* out = (float*)d_out;

  hipFuncSetAttribute(reinterpret_cast<const void*>(k_step),
                      hipFuncAttributeMaxDynamicSharedMemorySize, SMEM_TOT);

  char* hpad0 = ws + WS_HC;
  char* cpad0 = ws + WS_HC + (size_t)4*IMG_BYTES;
  char* hpad1 = ws + WS_HC + (size_t)8*IMG_BYTES;
  char* cpad1 = ws + WS_HC + (size_t)12*IMG_BYTES;

  /* zero h/c ping-pong (halos) each call (graph-safe); cstate via t0 branch */
  hipMemsetAsync(ws + WS_HC, 0, (size_t)16*IMG_BYTES, stream);

  k_xt<<<4224, 256, 0, stream>>>(x, ws + WS_BNXP);
  k_stats<<<256, 256, 0, stream>>>(ws + WS_BNXP, (float*)(ws + WS_PARTB));
  k_red<<<128, 256, 0, stream>>>((const float*)(ws + WS_PARTB),
                                 (float*)(ws + WS_PART2));
  k_bnfin<<<1, 64, 0, stream>>>((const float*)(ws + WS_PART2), gamma, beta,
                                (float*)(ws + WS_SCALE), (float*)(ws + WS_SHIFT));
  k_wt<<<1296, 256, 0, stream>>>(c1w, wc2h, wh2h,
                                 (const float*)(ws + WS_SCALE), (u16*)(ws + WS_WA));
  k_bias<<<192, 64, 0, stream>>>(c1w, c1b, (const float*)(ws + WS_SHIFT),
                                 (float*)(ws + WS_BTAB));

  for (int t = 0; t < 16; ++t){
    const char* cs = (t & 1) ? cpad1 : cpad0;
    const char* hs = (t & 1) ? hpad1 : hpad0;
    char* cd = (t & 1) ? cpad0 : cpad1;
    char* hd = (t & 1) ? hpad0 : hpad1;
    k_step<<<256, 512, SMEM_TOT, stream>>>(ws + WS_BNXP, cs, hs, cd, hd,
                                           ws + WS_WA,
                                           (const float*)(ws + WS_BTAB),
                                           (float*)(ws + WS_CSTATE), out, t);
  }
}